// Round 18
// baseline (84.493 us; speedup 1.0000x reference)
//
#include <hip/hip_runtime.h>

// ---------------------------------------------------------------------------
// MS Deformable Attention (Deformable-DETR), MI355X gfx950.  THREE kernels:
//   1. merged : 1504 blocks — bid<1408: valueT = bf16(inpf@W_val^T+b_val)
//      (XCD-pinned mapping, LDS-transpose epilogue); bid>=1408: fused =
//      query @ [W_off|W_attn]^T + biases [4000x384] f32.
//   2. msout  = bilinear-sample(valueT, loc, softmax(logits)) -> f32
//   3. out    = msout @ W_out^T + b_out    [4000 x 256] f32
// NO cvt pre-pass: GEMMs stage f32 operands directly at BK=32 — the f32 row
// (32 x 4B = 128 B) is byte-identical to the proven bf16 BK=64 row, so the
// entire staging/swizzle geometry carries over unchanged (64 KB LDS,
// 2 blocks/CU — avoids R12's occupancy collapse). Fragments are converted
// in-register via v_cvt_pk_bf16_f32 (packing proven bit-exact in R12).
// ---------------------------------------------------------------------------

typedef __attribute__((ext_vector_type(4))) float f32x4;
typedef __attribute__((ext_vector_type(4))) unsigned int u32x4;
typedef __attribute__((ext_vector_type(8))) short bf16x8;
typedef __attribute__((ext_vector_type(4))) short bf16x4;

static __device__ __forceinline__ unsigned short f2bf(float f) {
    unsigned u = __builtin_bit_cast(unsigned, f);
    u += 0x7FFFu + ((u >> 16) & 1u);   // round-to-nearest-even
    return (unsigned short)(u >> 16);
}
static __device__ __forceinline__ float bflo(unsigned d) {
    return __builtin_bit_cast(float, d << 16);
}
static __device__ __forceinline__ float bfhi(unsigned d) {
    return __builtin_bit_cast(float, d & 0xffff0000u);
}
static __device__ __forceinline__ unsigned cvtpk(float lo, float hi) {
    unsigned r;
    asm("v_cvt_pk_bf16_f32 %0, %1, %2" : "=v"(r) : "v"(lo), "v"(hi));
    return r;
}
static __device__ __forceinline__ void gload_lds16(const void* g, void* l) {
    __builtin_amdgcn_global_load_lds(
        (const __attribute__((address_space(1))) void*)g,
        (__attribute__((address_space(3))) void*)l, 16, 0, 0);
}

// read one MFMA fragment (8 consecutive f32 k-elements of row R) from a
// swizzled f32 LDS tile and convert to bf16x8. Row stride 128 B; source
// unit u stored at LDS unit u^(R&7); R&7 == fr&7 for all fragment rows.
static __device__ __forceinline__ bf16x8 frag_f32(const char* base, int R,
                                                  int fq, int fr7) {
    const f32x4 x0 = *(const f32x4*)(base + (R << 7) + ((((fq << 1) | 0) ^ fr7) << 4));
    const f32x4 x1 = *(const f32x4*)(base + (R << 7) + ((((fq << 1) | 1) ^ fr7) << 4));
    u32x4 u = { cvtpk(x0[0], x0[1]), cvtpk(x0[2], x0[3]),
                cvtpk(x1[0], x1[1]), cvtpk(x1[2], x1[3]) };
    return __builtin_bit_cast(bf16x8, u);
}

// ---------------------------------------------------------------------------
// f32 GEMM via bf16 MFMA: C = A[M,K] @ B[N,K]^T + bias. BM=BN=128, BK=32,
// 4 waves 2x2, dbuf LDS (2 phases x (A 16K + B 16K) = 64 KB), global_load_lds
// staging with pre-XOR'd source, one __syncthreads/iter, 16 MFMA/iter.
// MODE 0: out projection — C f32 [M,N], bias[col], 2D grid.
// MODE 3: merged — bid<1408: value path (XCD-pinned, LDS-transpose epilogue
//         -> valueT bf16); bid>=1408: fused path (A2, dual B source B2a/B2b,
//         dual bias bias2/bias3, C=Cv2, M=4000 N=384).
// ---------------------------------------------------------------------------
template<int MODE>
__global__ __launch_bounds__(256)
void gemm_k(const float* __restrict__ A,   const float* __restrict__ B,
            const float* __restrict__ A2,  const float* __restrict__ B2a,
            const float* __restrict__ B2b,
            const float* __restrict__ bias, const float* __restrict__ bias2,
            const float* __restrict__ bias3,
            void* __restrict__ Cv, void* __restrict__ Cv2,
            int M, int N, int K) {
    __shared__ __align__(16) char smem[65536];   // 2 phases x (As+Bs)

    const int tid = threadIdx.x, lane = tid & 63, w = tid >> 6;
    const int wm = w >> 1, wn = w & 1;

    const float* Ap = A;
    bool vmode = false;
    int bm, bn;
    if (MODE == 3) {
        const int bid = blockIdx.x;
        if (bid < 1408) {                // value path
            vmode = true;
            const int xcd = bid & 7;
            const int j   = bid >> 3;    // 0..175
            bm = xcd * 44 + (j >> 2);    // 8 XCDs x 44 groups = 352
            bn = j & 3;
        } else {                         // fused path
            const int r = bid - 1408;    // 0..95
            bm = r & 31; bn = r >> 5;    // 32 x 3
            Ap = A2;
            M = 4000; N = 384;
        }
    } else {
        bm = blockIdx.x; bn = blockIdx.y;
    }

    // staging map (byte-identical to proven bf16 BK=64): LDS byte
    // (j*4096 + w*1024 + lane*16) -> row j*32+w*8+(lane>>3);
    // source 16B-unit (lane&7) ^ (row&7). f32 row = 32 cols * 4B = 128 B.
    const int r8 = lane >> 3;
    const int colsrc = (((lane & 7) ^ r8) << 4);
    const char* pa[4]; const char* pb[4];
#pragma unroll
    for (int j = 0; j < 4; j++) {
        int ra = bm * 128 + j * 32 + w * 8 + r8; ra = ra < M ? ra : M - 1;
        int rb = bn * 128 + j * 32 + w * 8 + r8; rb = rb < N ? rb : N - 1;
        const float* bs = (MODE == 3 && !vmode) ? B2a : B;
        if (MODE == 3 && !vmode && rb >= 256) { bs = B2b; rb -= 256; }
        pa[j] = (const char*)Ap + (size_t)ra * ((size_t)K * 4) + colsrc;
        pb[j] = (const char*)bs + (size_t)rb * ((size_t)K * 4) + colsrc;
    }
    const int ldso = w << 10;
    const int NT = K >> 5;               // BK=32

    f32x4 acc[4][4] = {};
    const int fr = lane & 15, fq = lane >> 4;
    const int fr7 = fr & 7;

#pragma unroll
    for (int j = 0; j < 4; j++) {
        gload_lds16(pa[j], smem + j * 4096 + ldso);
        gload_lds16(pb[j], smem + 16384 + j * 4096 + ldso);
    }
    __syncthreads();   // tile 0 visible

    for (int t = 0; t < NT; ++t) {
        const int cur = (t & 1) << 15;
        if (t + 1 < NT) {
            const int nxt = ((t + 1) & 1) << 15;
            const int off = (t + 1) << 7;   // 32 f32 = 128 B per K-tile
#pragma unroll
            for (int j = 0; j < 4; j++) {
                gload_lds16(pa[j] + off, smem + nxt + j * 4096 + ldso);
                gload_lds16(pb[j] + off, smem + nxt + 16384 + j * 4096 + ldso);
            }
        }
        bf16x8 af[4], bv[4];
#pragma unroll
        for (int m = 0; m < 4; m++)
            af[m] = frag_f32(smem + cur, wm * 64 + m * 16 + fr, fq, fr7);
#pragma unroll
        for (int nn = 0; nn < 4; nn++)
            bv[nn] = frag_f32(smem + cur + 16384, wn * 64 + nn * 16 + fr, fq, fr7);
#pragma unroll
        for (int m = 0; m < 4; m++)
#pragma unroll
            for (int nn = 0; nn < 4; nn++)
                acc[m][nn] = __builtin_amdgcn_mfma_f32_16x16x32_bf16(
                    af[m], bv[nn], acc[m][nn], 0, 0, 0);
        __syncthreads();
    }

    if (MODE == 0 || !vmode) {
        // f32 row-major epilogue; fused path: dual bias (col>=256 -> bias3)
        float* C = (MODE == 3) ? (float*)Cv2 : (float*)Cv;
        const float* b1 = (MODE == 3) ? bias2 : bias;
        const int crow0 = bm * 128 + wm * 64 + fq * 4;
        const int ccol0 = bn * 128 + wn * 64 + fr;
#pragma unroll
        for (int m = 0; m < 4; m++) {
#pragma unroll
            for (int nn = 0; nn < 4; nn++) {
                const int col = ccol0 + nn * 16;
                const float bv2 = (MODE == 3 && col >= 256) ? bias3[col - 256]
                                                            : b1[col];
#pragma unroll
                for (int j = 0; j < 4; j++) {
                    const int row = crow0 + m * 16 + j;
                    if (row < M) C[(size_t)row * N + col] = acc[m][nn][j] + bv2;
                }
            }
        }
    } else {
        // per-wave LDS transpose epilogue (proven) -> valueT bf16
        unsigned short* tile = (unsigned short*)smem + (size_t)w * (64 * 68);
        const int hh = bn * 2 + wn;                 // head, uniform per wave
        float bvs[4];
#pragma unroll
        for (int nn = 0; nn < 4; nn++) bvs[nn] = bias[hh * 64 + nn * 16 + fr];
#pragma unroll
        for (int m = 0; m < 4; m++)
#pragma unroll
            for (int nn = 0; nn < 4; nn++)
#pragma unroll
                for (int j = 0; j < 4; j++)
                    tile[(m * 16 + fq * 4 + j) * 68 + nn * 16 + fr] =
                        f2bf(acc[m][nn][j] + bvs[nn]);
        __syncthreads();
        unsigned short* VT = (unsigned short*)Cv;
        const int q4 = (lane & 15) * 4;
        const int prow = lane >> 4;                 // 0..3
#pragma unroll
        for (int it = 0; it < 16; ++it) {
            const int pl = it * 4 + prow;           // local pixel 0..63
            const int pixg = bm * 128 + wm * 64 + pl;
            if (pixg < M) {
                const int n = pixg / 11253;
                const int pix = pixg - n * 11253;
                bf16x4 v = *(const bf16x4*)&tile[pl * 68 + q4];
                *(bf16x4*)(VT + ((size_t)(n * 8 + hh) * 11253 + pix) * 64 + q4) = v;
            }
        }
    }
}

// ---------------------------------------------------------------------------
// Sampling (R17-proven): one wave per (n, q, h), XCD-pinned slices; 16-group
// shfl_xor softmax; lane-parallel bilinear metadata; __shfl-broadcast gathers
// (indices stay in INT registers). Output msout now f32.
// ---------------------------------------------------------------------------
__global__ __launch_bounds__(256)
void sample_k(const unsigned short* __restrict__ valueT, // [4][8][11253][64] bf16
              const float* __restrict__ refp,            // [4][1000][4][2]
              const float* __restrict__ fused,           // [4][1000][384]
              float* __restrict__ msout)                 // [4][1000][512] f32
{
    const int bid = blockIdx.x;          // 0..7999
    const int xcd = bid & 7;
    const int jj  = bid >> 3;            // 0..999
    const int sl  = jj / 250;            // 0..3
    const int qb  = jj - sl * 250;       // 0..249
    const int nh  = xcd * 4 + sl;        // 0..31 (= n*8 + h)
    const int q   = __builtin_amdgcn_readfirstlane(qb * 4 + (threadIdx.x >> 6));
    const int lane = threadIdx.x & 63;
    const int g    = lane >> 5;          // x-corner group (0: xb, 1: xb+1)
    const int n = nh >> 3, h = nh & 7;
    const int nq = n * 1000 + q;

    // per-point metadata on lane groups of 16 (lanes 0-31 are the sources)
    const int p  = lane & 15;
    const int lv = p >> 2;
    const int W  = lv == 0 ? 92 : lv == 1 ? 46 : lv == 2 ? 23 : 12;  // H == W
    const int st = lv == 0 ? 0 : lv == 1 ? 8464 : lv == 2 ? 10580 : 11109;

    // softmax over the 16 points: group-parallel shfl_xor reduction
    const float lg = fused[(size_t)nq * 384 + 256 + h * 16 + p];
    float mx = lg;
#pragma unroll
    for (int sft = 1; sft < 16; sft <<= 1) mx = fmaxf(mx, __shfl_xor(mx, sft));
    const float e = __expf(lg - mx);
    float sum = e;
#pragma unroll
    for (int sft = 1; sft < 16; sft <<= 1) sum += __shfl_xor(sum, sft);
    const float a = e / sum;

    const float rx = refp[(size_t)nq * 8 + lv * 2 + 0];
    const float ry = refp[(size_t)nq * 8 + lv * 2 + 1];
    const float ox = fused[(size_t)nq * 384 + h * 32 + p * 2 + 0];
    const float oy = fused[(size_t)nq * 384 + h * 32 + p * 2 + 1];

    const float x = rx * (float)W + ox - 0.5f;
    const float y = ry * (float)W + oy - 0.5f;
    const float xf = floorf(x), yf = floorf(y);
    const int x0 = (int)xf, y0 = (int)yf;
    const float lx = x - xf, ly = y - yf;
    const int xb = min(max(x0, 0), W - 2);
    const int yb = min(max(y0, 0), W - 2);
    const float wx0 = (xb     == x0) ? (1.f - lx) : ((xb     == x0 + 1) ? lx : 0.f);
    const float wx1 = (xb + 1 == x0) ? (1.f - lx) : ((xb + 1 == x0 + 1) ? lx : 0.f);
    const float wy0 = (yb     == y0) ? (1.f - ly) : ((yb     == y0 + 1) ? ly : 0.f);
    const float wy1 = (yb + 1 == y0) ? (1.f - ly) : ((yb + 1 == y0 + 1) ? ly : 0.f);
    const int idx0v = st + yb * W + xb;
    const float wxs = (lane & 16) ? wx1 : wx0;   // lane group picks its x-corner
    const float wav = a * wxs * wy0;
    const float wbv = a * wxs * wy1;

    const unsigned int* vb =
        (const unsigned int*)valueT + (size_t)nh * 11253 * 32;

    float acc0 = 0.f, acc1 = 0.f;
    const int srcb = g << 4;
#pragma unroll
    for (int pp = 0; pp < 16; pp++) {
        const int Wc = pp < 4 ? 92 : pp < 8 ? 46 : pp < 12 ? 23 : 12;
        const int src = pp + srcb;           // lane pp (g=0) or pp+16 (g=1)
        const int   i0 = __shfl(idx0v, src);
        const float w0 = __shfl(wav,   src);
        const float w1 = __shfl(wbv,   src);
        const int   i1 = i0 + Wc;            // y+1 row, compile-time stride
        const unsigned d0 = vb[i0 * 32 + lane];   // lane>=32 reads pixel+1
        const unsigned d1 = vb[i1 * 32 + lane];
        acc0 = fmaf(w0, bflo(d0), acc0);
        acc1 = fmaf(w0, bfhi(d0), acc1);
        acc0 = fmaf(w1, bflo(d1), acc0);
        acc1 = fmaf(w1, bfhi(d1), acc1);
    }

    acc0 += __shfl(acc0, lane ^ 32);
    acc1 += __shfl(acc1, lane ^ 32);
    if (lane < 32) {
        float2 v2 = make_float2(acc0, acc1);
        *(float2*)&msout[(size_t)nq * 512 + h * 64 + (lane & 31) * 2] = v2;
    }
}

// ---------------------------------------------------------------------------
extern "C" void kernel_launch(void* const* d_in, const int* in_sizes, int n_in,
                              void* d_out, int out_size, void* d_ws, size_t ws_size,
                              hipStream_t stream) {
    (void)in_sizes; (void)n_in; (void)out_size; (void)ws_size;

    const float* query  = (const float*)d_in[0];
    const float* refp   = (const float*)d_in[1];
    const float* inpf   = (const float*)d_in[2];
    const float* W_off  = (const float*)d_in[5];
    const float* b_off  = (const float*)d_in[6];
    const float* W_attn = (const float*)d_in[7];
    const float* b_attn = (const float*)d_in[8];
    const float* W_val  = (const float*)d_in[9];
    const float* b_val  = (const float*)d_in[10];
    const float* W_out  = (const float*)d_in[11];
    const float* b_out  = (const float*)d_in[12];
    float* out = (float*)d_out;

    char* ws = (char*)d_ws;
    unsigned short* valueT = (unsigned short*)ws;            // 46,092,288 B
    float* fusedb = (float*)(ws + 46092288);                 //  6,144,000 B
    float* msoutf = (float*)(ws + 52236288);                 //  8,192,000 B

    // 1. merged: value projection (1408 blocks, f32 operands) + fused
    //    offsets/logits (96 blocks, dual B source W_off/W_attn)
    gemm_k<3><<<1504, 256, 0, stream>>>(
        inpf, W_val, query, W_off, W_attn, b_val, b_off, b_attn,
        valueT, fusedb, 45012, 512, 256);
    // 2. sampling (fused softmax), msout f32
    sample_k<<<8000, 256, 0, stream>>>(valueT, refp, fusedb, msoutf);
    // 3. output projection (A = msout f32, B = W_out f32, K=512)
    gemm_k<0><<<dim3(32, 2), 256, 0, stream>>>(
        msoutf, W_out, nullptr, nullptr, nullptr, b_out, nullptr, nullptr,
        out, nullptr, 4000, 256, 512);
}

// Round 19
// 81.205 us; speedup vs baseline: 1.0405x; 1.0405x over previous
//
#include <hip/hip_runtime.h>

// ---------------------------------------------------------------------------
// MS Deformable Attention (Deformable-DETR), MI355X gfx950.
//   0. cvt    : all f32 operands -> bf16 (one streaming kernel)
//   1. merged : 1504 blocks — bid<1408: valueT = bf16(inpf@W_val^T+b_val)
//      (XCD-pinned mapping, LDS-transpose epilogue); bid>=1408: fused =
//      query @ [W_off|W_attn]^T + biases [4000x384] f32.
//   2. msout  = bilinear-sample(valueT, loc, softmax(logits)) -> bf16
//      (shfl transport; weights bf16-packed -> 2 shfls/point instead of 3)
//   3. out    = msout @ W_out^T + b_out    [4000 x 256] f32
// vs R17 (83.7 us proven): ONLY the gather-loop weight packing changed.
// ---------------------------------------------------------------------------

typedef __attribute__((ext_vector_type(4))) float f32x4;
typedef __attribute__((ext_vector_type(8))) short bf16x8;
typedef __attribute__((ext_vector_type(4))) short bf16x4;

static __device__ __forceinline__ unsigned short f2bf(float f) {
    unsigned u = __builtin_bit_cast(unsigned, f);
    u += 0x7FFFu + ((u >> 16) & 1u);   // round-to-nearest-even
    return (unsigned short)(u >> 16);
}
static __device__ __forceinline__ float bflo(unsigned d) {
    return __builtin_bit_cast(float, d << 16);
}
static __device__ __forceinline__ float bfhi(unsigned d) {
    return __builtin_bit_cast(float, d & 0xffff0000u);
}
static __device__ __forceinline__ unsigned cvtpk(float lo, float hi) {
    unsigned r;
    asm("v_cvt_pk_bf16_f32 %0, %1, %2" : "=v"(r) : "v"(lo), "v"(hi));
    return r;
}
static __device__ __forceinline__ void gload_lds16(const void* g, void* l) {
    __builtin_amdgcn_global_load_lds(
        (const __attribute__((address_space(1))) void*)g,
        (__attribute__((address_space(3))) void*)l, 16, 0, 0);
}

// ---------------------------------------------------------------------------
// f32 -> bf16 conversion of all operands into one packed buffer (proven).
//   inpf 0 | query 11523072 | W_off 12547072 | W_attn 12612608
//   | W_val 12645376 | W_out 12776448 | total 12907520
// ---------------------------------------------------------------------------
__global__ __launch_bounds__(256)
void cvt_k(const float* __restrict__ s0, const float* __restrict__ s1,
           const float* __restrict__ s2, const float* __restrict__ s3,
           const float* __restrict__ s4, const float* __restrict__ s5,
           unsigned short* __restrict__ dst) {
    const size_t i8 = ((size_t)blockIdx.x * 256 + threadIdx.x) * 8;
    if (i8 >= 12907520u) return;
    const float* sp; size_t loc;
    if (i8 < 11523072u)      { sp = s0; loc = i8; }
    else if (i8 < 12547072u) { sp = s1; loc = i8 - 11523072u; }
    else if (i8 < 12612608u) { sp = s2; loc = i8 - 12547072u; }
    else if (i8 < 12645376u) { sp = s3; loc = i8 - 12612608u; }
    else if (i8 < 12776448u) { sp = s4; loc = i8 - 12645376u; }
    else                     { sp = s5; loc = i8 - 12776448u; }
    f32x4 a = *(const f32x4*)(sp + loc);
    f32x4 b = *(const f32x4*)(sp + loc + 4);
    bf16x8 r;
    r[0] = f2bf(a[0]); r[1] = f2bf(a[1]); r[2] = f2bf(a[2]); r[3] = f2bf(a[3]);
    r[4] = f2bf(b[0]); r[5] = f2bf(b[1]); r[6] = f2bf(b[2]); r[7] = f2bf(b[3]);
    *(bf16x8*)(dst + i8) = r;
}

// ---------------------------------------------------------------------------
// bf16 GEMM (R16/R17-proven): BM=BN=128, BK=64, 4 waves 2x2, dbuf LDS,
// global_load_lds staging with pre-XOR'd source, one __syncthreads/iter.
// MODE 0: out projection — C f32 [M,N], bias[col], 2D grid.
// MODE 3: merged — bid<1408: value path (XCD-pinned, LDS-transpose epilogue);
//         bid>=1408: fused path (A2/B2, dual bias, C=Cv2, M=4000 N=384).
// ---------------------------------------------------------------------------
template<int MODE>
__global__ __launch_bounds__(256)
void gemm_bf16_tn(const unsigned short* __restrict__ A,
                  const unsigned short* __restrict__ B,
                  const unsigned short* __restrict__ A2,
                  const unsigned short* __restrict__ B2,
                  const float* __restrict__ bias, const float* __restrict__ bias2,
                  const float* __restrict__ bias3,
                  void* __restrict__ Cv, void* __restrict__ Cv2,
                  int M, int N, int K) {
    __shared__ __align__(16) char smem[65536];   // 2 phases x (As+Bs)

    const int tid = threadIdx.x, lane = tid & 63, w = tid >> 6;
    const int wm = w >> 1, wn = w & 1;

    const unsigned short* Ap = A;
    const unsigned short* Bp = B;
    bool vmode = false;
    int bm, bn;
    if (MODE == 3) {
        const int bid = blockIdx.x;
        if (bid < 1408) {                // value path
            vmode = true;
            const int xcd = bid & 7;
            const int j   = bid >> 3;    // 0..175
            bm = xcd * 44 + (j >> 2);    // 8 XCDs x 44 groups = 352
            bn = j & 3;
        } else {                         // fused path
            const int r = bid - 1408;    // 0..95
            bm = r & 31; bn = r >> 5;    // 32 x 3
            Ap = A2; Bp = B2;
            M = 4000; N = 384;
        }
    } else {
        bm = blockIdx.x; bn = blockIdx.y;
    }

    const int r8 = lane >> 3;
    const int colsrc = (((lane & 7) ^ r8) << 4);
    const char* pa[4]; const char* pb[4];
#pragma unroll
    for (int j = 0; j < 4; j++) {
        int ra = bm * 128 + j * 32 + w * 8 + r8; ra = ra < M ? ra : M - 1;
        int rb = bn * 128 + j * 32 + w * 8 + r8; rb = rb < N ? rb : N - 1;
        pa[j] = (const char*)Ap + (size_t)ra * ((size_t)K * 2) + colsrc;
        pb[j] = (const char*)Bp + (size_t)rb * ((size_t)K * 2) + colsrc;
    }
    const int ldso = w << 10;
    const int NT = K >> 6;

    f32x4 acc[4][4] = {};
    const int fr = lane & 15, fq = lane >> 4;
    const int k8b = fq << 4;
    const int swzR = (fr & 7) << 4;

#pragma unroll
    for (int j = 0; j < 4; j++) {
        gload_lds16(pa[j], smem + j * 4096 + ldso);
        gload_lds16(pb[j], smem + 16384 + j * 4096 + ldso);
    }
    __syncthreads();   // tile 0 visible

    for (int t = 0; t < NT; ++t) {
        const int cur = (t & 1) << 15;
        if (t + 1 < NT) {
            const int nxt = ((t + 1) & 1) << 15;
            const int off = (t + 1) << 7;
#pragma unroll
            for (int j = 0; j < 4; j++) {
                gload_lds16(pa[j] + off, smem + nxt + j * 4096 + ldso);
                gload_lds16(pb[j] + off, smem + nxt + 16384 + j * 4096 + ldso);
            }
        }
#pragma unroll
        for (int kk = 0; kk < 2; ++kk) {
            const int ko = ((kk << 6) + k8b) ^ swzR;
            bf16x8 af[4], bv[4];
#pragma unroll
            for (int m = 0; m < 4; m++)
                af[m] = *(const bf16x8*)(smem + cur + ((wm * 64 + m * 16 + fr) << 7) + ko);
#pragma unroll
            for (int nn = 0; nn < 4; nn++)
                bv[nn] = *(const bf16x8*)(smem + cur + 16384 + ((wn * 64 + nn * 16 + fr) << 7) + ko);
#pragma unroll
            for (int m = 0; m < 4; m++)
#pragma unroll
                for (int nn = 0; nn < 4; nn++)
                    acc[m][nn] = __builtin_amdgcn_mfma_f32_16x16x32_bf16(
                        af[m], bv[nn], acc[m][nn], 0, 0, 0);
        }
        __syncthreads();
    }

    if (MODE == 0 || !vmode) {
        float* C = (MODE == 3) ? (float*)Cv2 : (float*)Cv;
        const float* b1 = (MODE == 3) ? bias2 : bias;
        const int crow0 = bm * 128 + wm * 64 + fq * 4;
        const int ccol0 = bn * 128 + wn * 64 + fr;
#pragma unroll
        for (int m = 0; m < 4; m++) {
#pragma unroll
            for (int nn = 0; nn < 4; nn++) {
                const int col = ccol0 + nn * 16;
                const float bv2 = (MODE == 3 && col >= 256) ? bias3[col - 256]
                                                            : b1[col];
#pragma unroll
                for (int j = 0; j < 4; j++) {
                    const int row = crow0 + m * 16 + j;
                    if (row < M) C[(size_t)row * N + col] = acc[m][nn][j] + bv2;
                }
            }
        }
    } else {
        // per-wave LDS transpose epilogue (proven) -> valueT
        unsigned short* tile = (unsigned short*)smem + (size_t)w * (64 * 68);
        const int hh = bn * 2 + wn;                 // head, uniform per wave
        float bvs[4];
#pragma unroll
        for (int nn = 0; nn < 4; nn++) bvs[nn] = bias[hh * 64 + nn * 16 + fr];
#pragma unroll
        for (int m = 0; m < 4; m++)
#pragma unroll
            for (int nn = 0; nn < 4; nn++)
#pragma unroll
                for (int j = 0; j < 4; j++)
                    tile[(m * 16 + fq * 4 + j) * 68 + nn * 16 + fr] =
                        f2bf(acc[m][nn][j] + bvs[nn]);
        __syncthreads();
        unsigned short* VT = (unsigned short*)Cv;
        const int q4 = (lane & 15) * 4;
        const int prow = lane >> 4;                 // 0..3
#pragma unroll
        for (int it = 0; it < 16; ++it) {
            const int pl = it * 4 + prow;           // local pixel 0..63
            const int pixg = bm * 128 + wm * 64 + pl;
            if (pixg < M) {
                const int n = pixg / 11253;
                const int pix = pixg - n * 11253;
                bf16x4 v = *(const bf16x4*)&tile[pl * 68 + q4];
                *(bf16x4*)(VT + ((size_t)(n * 8 + hh) * 11253 + pix) * 64 + q4) = v;
            }
        }
    }
}

// ---------------------------------------------------------------------------
// Sampling: one wave per (n, q, h), XCD-pinned slices (proven mapping).
// 16-group shfl_xor softmax; lane-parallel bilinear metadata; shfl-broadcast
// gathers with bf16-PACKED weights: 2 shfls/point (i0 + packed w0|w1),
// unpacked by 2 VALU ops. i1 = i0 + W (compile-time level width).
// ---------------------------------------------------------------------------
__global__ __launch_bounds__(256)
void sample_k(const unsigned short* __restrict__ valueT, // [4][8][11253][64] bf16
              const float* __restrict__ refp,            // [4][1000][4][2]
              const float* __restrict__ fused,           // [4][1000][384]
              unsigned int* __restrict__ msout)          // [4][1000][256] dwords
{
    const int bid = blockIdx.x;          // 0..7999
    const int xcd = bid & 7;
    const int jj  = bid >> 3;            // 0..999
    const int sl  = jj / 250;            // 0..3
    const int qb  = jj - sl * 250;       // 0..249
    const int nh  = xcd * 4 + sl;        // 0..31 (= n*8 + h)
    const int q   = __builtin_amdgcn_readfirstlane(qb * 4 + (threadIdx.x >> 6));
    const int lane = threadIdx.x & 63;
    const int g    = lane >> 5;          // x-corner group (0: xb, 1: xb+1)
    const int n = nh >> 3, h = nh & 7;
    const int nq = n * 1000 + q;

    // per-point metadata on lane groups of 16 (lanes 0-31 are the sources)
    const int p  = lane & 15;
    const int lv = p >> 2;
    const int W  = lv == 0 ? 92 : lv == 1 ? 46 : lv == 2 ? 23 : 12;  // H == W
    const int st = lv == 0 ? 0 : lv == 1 ? 8464 : lv == 2 ? 10580 : 11109;

    // softmax over the 16 points: group-parallel shfl_xor reduction
    const float lg = fused[(size_t)nq * 384 + 256 + h * 16 + p];
    float mx = lg;
#pragma unroll
    for (int sft = 1; sft < 16; sft <<= 1) mx = fmaxf(mx, __shfl_xor(mx, sft));
    const float e = __expf(lg - mx);
    float sum = e;
#pragma unroll
    for (int sft = 1; sft < 16; sft <<= 1) sum += __shfl_xor(sum, sft);
    const float a = e / sum;

    const float rx = refp[(size_t)nq * 8 + lv * 2 + 0];
    const float ry = refp[(size_t)nq * 8 + lv * 2 + 1];
    const float ox = fused[(size_t)nq * 384 + h * 32 + p * 2 + 0];
    const float oy = fused[(size_t)nq * 384 + h * 32 + p * 2 + 1];

    const float x = rx * (float)W + ox - 0.5f;
    const float y = ry * (float)W + oy - 0.5f;
    const float xf = floorf(x), yf = floorf(y);
    const int x0 = (int)xf, y0 = (int)yf;
    const float lx = x - xf, ly = y - yf;
    const int xb = min(max(x0, 0), W - 2);
    const int yb = min(max(y0, 0), W - 2);
    const float wx0 = (xb     == x0) ? (1.f - lx) : ((xb     == x0 + 1) ? lx : 0.f);
    const float wx1 = (xb + 1 == x0) ? (1.f - lx) : ((xb + 1 == x0 + 1) ? lx : 0.f);
    const float wy0 = (yb     == y0) ? (1.f - ly) : ((yb     == y0 + 1) ? ly : 0.f);
    const float wy1 = (yb + 1 == y0) ? (1.f - ly) : ((yb + 1 == y0 + 1) ? ly : 0.f);
    const int idx0v = st + yb * W + xb;
    const float wxs = (lane & 16) ? wx1 : wx0;   // lane group picks its x-corner
    // pack the two row-weights as bf16 pair: lo = w(y0), hi = w(y0+1)
    const unsigned cw = cvtpk(a * wxs * wy0, a * wxs * wy1);

    const unsigned int* vb =
        (const unsigned int*)valueT + (size_t)nh * 11253 * 32;

    float acc0 = 0.f, acc1 = 0.f;
    const int srcb = g << 4;
#pragma unroll
    for (int pp = 0; pp < 16; pp++) {
        const int Wc = pp < 4 ? 92 : pp < 8 ? 46 : pp < 12 ? 23 : 12;
        const int src = pp + srcb;           // lane pp (g=0) or pp+16 (g=1)
        const int      i0  = __shfl(idx0v, src);
        const unsigned cwp = (unsigned)__shfl((int)cw, src);
        const float w0 = bflo(cwp);          // w(y0)
        const float w1 = bfhi(cwp);          // w(y0+1)
        const int   i1 = i0 + Wc;            // y+1 row, compile-time stride
        const unsigned d0 = vb[i0 * 32 + lane];   // lane>=32 reads pixel+1
        const unsigned d1 = vb[i1 * 32 + lane];
        acc0 = fmaf(w0, bflo(d0), acc0);
        acc1 = fmaf(w0, bfhi(d0), acc1);
        acc0 = fmaf(w1, bflo(d1), acc0);
        acc1 = fmaf(w1, bfhi(d1), acc1);
    }

    acc0 += __shfl(acc0, lane ^ 32);
    acc1 += __shfl(acc1, lane ^ 32);
    if (lane < 32) {
        const unsigned u = (unsigned)f2bf(acc0) | ((unsigned)f2bf(acc1) << 16);
        msout[(size_t)nq * 256 + h * 32 + (lane & 31)] = u;
    }
}

// ---------------------------------------------------------------------------
extern "C" void kernel_launch(void* const* d_in, const int* in_sizes, int n_in,
                              void* d_out, int out_size, void* d_ws, size_t ws_size,
                              hipStream_t stream) {
    (void)in_sizes; (void)n_in; (void)out_size; (void)ws_size;

    const float* query  = (const float*)d_in[0];
    const float* refp   = (const float*)d_in[1];
    const float* inpf   = (const float*)d_in[2];
    const float* W_off  = (const float*)d_in[5];
    const float* b_off  = (const float*)d_in[6];
    const float* W_attn = (const float*)d_in[7];
    const float* b_attn = (const float*)d_in[8];
    const float* W_val  = (const float*)d_in[9];
    const float* b_val  = (const float*)d_in[10];
    const float* W_out  = (const float*)d_in[11];
    const float* b_out  = (const float*)d_in[12];
    float* out = (float*)d_out;

    char* ws = (char*)d_ws;
    unsigned short* bf = (unsigned short*)ws;                    // 25,815,040 B
    unsigned short* inpfb   = bf;
    unsigned short* queryb  = bf + 11523072;
    unsigned short* W_offb  = bf + 12547072;   // [W_off;W_attn] = [384 x 256]
    unsigned short* W_valb  = bf + 12645376;
    unsigned short* W_outb  = bf + 12776448;
    unsigned short* valueT  = (unsigned short*)(ws + 25815040);  // 46,092,288 B
    float* fusedb = (float*)(ws + 71907328);                     //  6,144,000 B
    unsigned int* msoutu = (unsigned int*)(ws + 78051328);       //  4,096,000 B
    unsigned short* msoutb = (unsigned short*)msoutu;

    // 0. convert everything to bf16
    cvt_k<<<6303, 256, 0, stream>>>(inpf, query, W_off, W_attn, W_val, W_out, bf);
    // 1. merged: value projection (1408 blocks) + fused off/logits (96 blocks)
    gemm_bf16_tn<3><<<1504, 256, 0, stream>>>(
        inpfb, W_valb, queryb, W_offb, b_val, b_off, b_attn,
        valueT, fusedb, 45012, 512, 256);
    // 2. sampling (fused softmax), msout bf16
    sample_k<<<8000, 256, 0, stream>>>(valueT, refp, fusedb, msoutu);
    // 3. output projection
    gemm_bf16_tn<0><<<dim3(32, 2), 256, 0, stream>>>(
        msoutb, W_outb, nullptr, nullptr, b_out, nullptr, nullptr,
        out, nullptr, 4000, 256, 512);
}